// Round 7
// baseline (61.182 us; speedup 1.0000x reference)
//
#include <hip/hip_runtime.h>

// Problem constants (UserContextAttentionPooler): U=128, I=256, J=512, C=E=128
#define UU 128
#define II 256
#define JJ 512
#define CC 128
#define EE 128
#define IB 16            // i-rows per block
#define NIB 16           // i-tiles per u
#define JT 64            // j per V tile
#define NJT 8            // V tiles per u
#define VTP 72           // (fallback kernel) Vt row stride in shorts

typedef short bf16x8 __attribute__((ext_vector_type(8)));
typedef float f32x4 __attribute__((ext_vector_type(4)));

union FragU { bf16x8 v; unsigned u[4]; };

__device__ __forceinline__ float fast_tanh(float x) {
    float ex = __expf(2.0f * x);
    return 1.0f - 2.0f / (ex + 1.0f);
}

__device__ __forceinline__ unsigned pack_bf16x2(float lo, float hi) {
    unsigned ul = __float_as_uint(lo), uh = __float_as_uint(hi);
    ul = (ul + 0x7FFFu + ((ul >> 16) & 1u)) >> 16;
    uh = (uh + 0x7FFFu + ((uh >> 16) & 1u)) >> 16;
    return ul | (uh << 16);
}

__device__ __forceinline__ short bf16s(float f) {
    unsigned u = __float_as_uint(f);
    u = (u + 0x7FFFu + ((u >> 16) & 1u)) >> 16;
    return (short)u;
}

__device__ __forceinline__ float wave_reduce_add(float v) {
#pragma unroll
    for (int k = 32; k >= 1; k >>= 1) v += __shfl_xor(v, k, 64);
    return v;
}

// ---------------------------------------------------------------------------
// Kernel A: VT pass (vt_g bf16 B-tiles + s_k, itc read once; writer XCD ==
// consumer XCD == u%8), u_part (U,C)[+b_mlp], wt_g = bf16 W_mlp[E:] B-frags.
// Vt tile (u,jt), short idx: kk*4096 + c*32 + (j&31); a wave B-frag load is
// a contiguous 1KB region.
// ---------------------------------------------------------------------------
#define VT_BLOCKS (UU * NJT)      // 1024 (must stay multiple of 8 at offset 0)
#define UP_BLOCKS (UU * CC / 256) // 64

__global__ void precompute_kernel(const float* __restrict__ itc,
                                  const float* __restrict__ user,
                                  const float* __restrict__ wd,
                                  const float* __restrict__ Wm,
                                  const float* __restrict__ bm,
                                  float* __restrict__ sk_g,
                                  float* __restrict__ up_g,
                                  short* __restrict__ vtg,
                                  short* __restrict__ wtg) {
    __shared__ float vt_f[JT][CC + 4];
    int b = blockIdx.x;
    int t = threadIdx.x;
    if (b < VT_BLOCKS) {
        int u = b & 127, jt = b >> 7;   // u fast -> writer XCD = u%8
        const float* src = itc + ((size_t)u * JJ + jt * JT) * CC;
#pragma unroll
        for (int k = 0; k < 8; ++k) {
            int f = t + 256 * k;
            int row = f >> 5, c4 = (f & 31) * 4;
            *(float4*)&vt_f[row][c4] = *(const float4*)&src[(size_t)row * CC + c4];
        }
        __syncthreads();
        // s_k for these 64 rows (4 threads per row)
        {
            int r = t >> 2, q4 = t & 3;
            float s = 0.f;
#pragma unroll
            for (int cc = 0; cc < 32; cc += 4) {
                float4 a = *(const float4*)&vt_f[r][q4 * 32 + cc];
                float4 w = *(const float4*)&wd[CC + q4 * 32 + cc];
                s += a.x * w.x + a.y * w.y + a.z * w.z + a.w * w.w;
            }
            s += __shfl_xor(s, 1, 64);
            s += __shfl_xor(s, 2, 64);
            if (q4 == 0) sk_g[u * JJ + jt * JT + r] = s;
        }
        // pack transposed bf16 tile: [kk][c][j&31]
        {
            int c = t & 127, half = t >> 7;
            unsigned* dst = (unsigned*)(vtg + (size_t)(u * NJT + jt) * 8192) +
                            half * 2048 + c * 16;
#pragma unroll
            for (int m = 0; m < 16; ++m) {
                dst[m] = pack_bf16x2(vt_f[32 * half + 2 * m][c],
                                     vt_f[32 * half + 2 * m + 1][c]);
            }
        }
    } else if (b < VT_BLOCKS + UP_BLOCKS) {
        int idx = (b - VT_BLOCKS) * 256 + t;
        int u = idx >> 7, c = idx & 127;
        float acc = bm[c];
#pragma unroll 8
        for (int e = 0; e < EE; ++e) acc += user[u * EE + e] * Wm[e * CC + c];
        up_g[idx] = acc;
    } else {
        // pack W_mlp[E:] (128x128) -> wt_g, B-frag order
        int n = t & 127, khalf = t >> 7;
#pragma unroll
        for (int ks2 = 0; ks2 < 2; ++ks2) {
            int ks = khalf * 2 + ks2;
#pragma unroll
            for (int g = 0; g < 4; ++g) {
                unsigned q[4];
#pragma unroll
                for (int pr = 0; pr < 4; ++pr) {
                    float lo = Wm[(size_t)(EE + 32 * ks + 8 * g + 2 * pr) * CC + n];
                    float hi = Wm[(size_t)(EE + 32 * ks + 8 * g + 2 * pr + 1) * CC + n];
                    q[pr] = pack_bf16x2(lo, hi);
                }
                *(uint4*)&wtg[ks * 4096 + n * 32 + 8 * g] =
                    make_uint4(q[0], q[1], q[2], q[3]);
            }
        }
    }
}

// ---------------------------------------------------------------------------
// Kernel B (main): one block per (u, 16-row i-tile), 256 threads = 4 waves.
// s_t computed in-block; p once per block -> swizzled bf16 LDS; attn written
// nontemporal from bf16 regs; B-prefetch issued BEFORE attn stores so MFMA
// waits allow stores in flight; mlp via MFMA on wt_g.
// ---------------------------------------------------------------------------
__global__ __launch_bounds__(256, 4) void fused_main(
    const float* __restrict__ tgt, const int* __restrict__ mask,
    const float* __restrict__ wd, const float* __restrict__ bd,
    const float* __restrict__ sk_g, const float* __restrict__ up_g,
    const short* __restrict__ vt_g, const short* __restrict__ wt_g,
    float* __restrict__ out_ctx, float* __restrict__ out_attn) {
    __shared__ __align__(16) short ps[8192];       // 16KB p tile (swizzled)
    __shared__ __align__(16) short pooled_bf[2048];// 4KB pooled tile (swizzled)
    __shared__ float dinv_lds[IB];

    int b = blockIdx.x;
    int x = b & 7, qq = b >> 3;
    int u = x + 8 * (qq >> 4);     // 16 blocks of a given u -> same XCD
    int ib = qq & 15;
    int i0 = ib * IB;
    int t = threadIdx.x;
    int w = t >> 6, l = t & 63, ln = l & 15, g = l >> 4;
    int r = t >> 4, s4 = t & 15;

    // ---- Phase 0: s_t in-block (row r, 16 threads per row) ----
    float sv;
    {
        const float* trow = tgt + ((size_t)(u * II + i0 + r)) * CC + s4 * 8;
        float4 t0 = *(const float4*)&trow[0];
        float4 t1 = *(const float4*)&trow[4];
        float4 w0 = *(const float4*)&wd[s4 * 8];
        float4 w1 = *(const float4*)&wd[s4 * 8 + 4];
        float part = t0.x * w0.x + t0.y * w0.y + t0.z * w0.z + t0.w * w0.w +
                     t1.x * w1.x + t1.y * w1.y + t1.z * w1.z + t1.w * w1.w;
        part += __shfl_xor(part, 1, 64);
        part += __shfl_xor(part, 2, 64);
        part += __shfl_xor(part, 4, 64);
        part += __shfl_xor(part, 8, 64);
        sv = part + bd[0];
    }

    // ---- Phase 1: p once per block; 32 elems/thread; bf16 kept in regs ----
    const float* skb = sk_g + u * JJ;
    const int* mkb = mask + u * JJ;
    unsigned pk[16];
    float rowsum = 0.f;
#pragma unroll
    for (int h = 0; h < 4; ++h) {
        int jb = 8 * (s4 + 16 * h);
        float4 k0 = *(const float4*)&skb[jb];
        float4 k1 = *(const float4*)&skb[jb + 4];
        int4 m0 = *(const int4*)&mkb[jb];
        int4 m1 = *(const int4*)&mkb[jb + 4];
        float p0 = m0.x ? __expf(fast_tanh(sv + k0.x)) : 0.f;
        float p1 = m0.y ? __expf(fast_tanh(sv + k0.y)) : 0.f;
        float p2 = m0.z ? __expf(fast_tanh(sv + k0.z)) : 0.f;
        float p3 = m0.w ? __expf(fast_tanh(sv + k0.w)) : 0.f;
        float p4 = m1.x ? __expf(fast_tanh(sv + k1.x)) : 0.f;
        float p5 = m1.y ? __expf(fast_tanh(sv + k1.y)) : 0.f;
        float p6 = m1.z ? __expf(fast_tanh(sv + k1.z)) : 0.f;
        float p7 = m1.w ? __expf(fast_tanh(sv + k1.w)) : 0.f;
        rowsum += p0 + p1 + p2 + p3 + p4 + p5 + p6 + p7;
        unsigned q0 = pack_bf16x2(p0, p1);
        unsigned q1 = pack_bf16x2(p2, p3);
        unsigned q2 = pack_bf16x2(p4, p5);
        unsigned q3 = pack_bf16x2(p6, p7);
        pk[4 * h + 0] = q0; pk[4 * h + 1] = q1;
        pk[4 * h + 2] = q2; pk[4 * h + 3] = q3;
        int gp = (s4 + 16 * h) ^ (r & 7);
        *(uint4*)((char*)ps + r * 1024 + 16 * gp) = make_uint4(q0, q1, q2, q3);
    }
    rowsum += __shfl_xor(rowsum, 1, 64);
    rowsum += __shfl_xor(rowsum, 2, 64);
    rowsum += __shfl_xor(rowsum, 4, 64);
    rowsum += __shfl_xor(rowsum, 8, 64);
    float dinv = 1.0f / rowsum;
    if (s4 == 0) dinv_lds[r] = dinv;

    // ---- Phase 3 prefetch FIRST (loads ahead of stores in VMEM queue) ----
    const short* b_base =
        vt_g + (size_t)u * (NJT * 8192) + (32 * w + ln) * 32 + 8 * g;
    bf16x8 pb0[8], pb1[8];
#pragma unroll
    for (int s = 0; s < 8; ++s) {
        int off = (s >> 1) * 8192 + (s & 1) * 4096;
        pb0[s] = *(const bf16x8*)&b_base[off];
        pb1[s] = *(const bf16x8*)&b_base[off + 512];
    }

    // ---- Phase 2: attn = bf16(p)*dinv, nontemporal (no L2 pollution) ----
    {
        float* ab = out_attn + ((size_t)(u * II + i0 + r)) * JJ;
#pragma unroll
        for (int h = 0; h < 4; ++h) {
            int jb = 8 * (s4 + 16 * h);
            unsigned q0 = pk[4 * h], q1 = pk[4 * h + 1];
            unsigned q2 = pk[4 * h + 2], q3 = pk[4 * h + 3];
            f32x4 v0, v1;
            v0[0] = __uint_as_float(q0 << 16) * dinv;
            v0[1] = __uint_as_float(q0 & 0xFFFF0000u) * dinv;
            v0[2] = __uint_as_float(q1 << 16) * dinv;
            v0[3] = __uint_as_float(q1 & 0xFFFF0000u) * dinv;
            v1[0] = __uint_as_float(q2 << 16) * dinv;
            v1[1] = __uint_as_float(q2 & 0xFFFF0000u) * dinv;
            v1[2] = __uint_as_float(q3 << 16) * dinv;
            v1[3] = __uint_as_float(q3 & 0xFFFF0000u) * dinv;
            __builtin_nontemporal_store(v0, (f32x4*)&ab[jb]);
            __builtin_nontemporal_store(v1, (f32x4*)&ab[jb + 4]);
        }
    }

    // LDS-only barrier (no vmcnt drain: stores + prefetch stay in flight)
    asm volatile("s_waitcnt lgkmcnt(0)" ::: "memory");
    __builtin_amdgcn_s_barrier();
    asm volatile("" ::: "memory");

    // ---- Phase 3: 16 MFMA steps, 8-deep register pipeline ----
    f32x4 acc0 = {0.f, 0.f, 0.f, 0.f};
    f32x4 acc1 = {0.f, 0.f, 0.f, 0.f};
#pragma unroll
    for (int s = 0; s < 16; ++s) {
        bf16x8 af = *(const bf16x8*)((const char*)ps + ln * 1024 +
                                     16 * ((4 * s + g) ^ (ln & 7)));
        acc0 = __builtin_amdgcn_mfma_f32_16x16x32_bf16(af, pb0[s & 7], acc0, 0, 0, 0);
        acc1 = __builtin_amdgcn_mfma_f32_16x16x32_bf16(af, pb1[s & 7], acc1, 0, 0, 0);
        if (s < 8) {
            int off = ((s + 8) >> 1) * 8192 + ((s + 8) & 1) * 4096;
            pb0[s & 7] = *(const bf16x8*)&b_base[off];
            pb1[s & 7] = *(const bf16x8*)&b_base[off + 512];
        }
    }

    // ---- Phase 5 W-frag prefetch (L2-hot 32KB, shared by all blocks) ----
    const short* wbase = wt_g + (32 * w + ln) * 32 + 8 * g;
    bf16x8 wb0[4], wb1[4];
#pragma unroll
    for (int ks = 0; ks < 4; ++ks) {
        wb0[ks] = *(const bf16x8*)&wbase[ks * 4096];
        wb1[ks] = *(const bf16x8*)&wbase[ks * 4096 + 512];
    }

    // ---- Phase 4: scale pooled by dinv, pack bf16 -> swizzled LDS ----
#pragma unroll
    for (int ri = 0; ri < 4; ++ri) {
        int row = 4 * g + ri;
        float dv = dinv_lds[row];
        int c0 = 32 * w + ln;
        int by0 = row * 256 + 16 * ((c0 >> 3) ^ (row & 7)) + 2 * (ln & 7);
        *(short*)((char*)pooled_bf + by0) = bf16s(acc0[ri] * dv);
        int c1 = c0 + 16;
        int by1 = row * 256 + 16 * ((c1 >> 3) ^ (row & 7)) + 2 * (ln & 7);
        *(short*)((char*)pooled_bf + by1) = bf16s(acc1[ri] * dv);
    }
    asm volatile("s_waitcnt lgkmcnt(0)" ::: "memory");
    __builtin_amdgcn_s_barrier();
    asm volatile("" ::: "memory");

    // ---- Phase 5: out = relu(u_part + pooled @ W_mlp[E:]) via MFMA ----
    f32x4 oa0 = {0.f, 0.f, 0.f, 0.f};
    f32x4 oa1 = {0.f, 0.f, 0.f, 0.f};
#pragma unroll
    for (int ks = 0; ks < 4; ++ks) {
        bf16x8 pa = *(const bf16x8*)((const char*)pooled_bf + ln * 256 +
                                     16 * ((4 * ks + g) ^ (ln & 7)));
        oa0 = __builtin_amdgcn_mfma_f32_16x16x32_bf16(pa, wb0[ks], oa0, 0, 0, 0);
        oa1 = __builtin_amdgcn_mfma_f32_16x16x32_bf16(pa, wb1[ks], oa1, 0, 0, 0);
    }
    {
        int c0 = 32 * w + ln, c1 = c0 + 16;
        float up0v = up_g[u * CC + c0];
        float up1v = up_g[u * CC + c1];
        float* ctx = out_ctx + ((size_t)(u * II + i0)) * CC;
#pragma unroll
        for (int ri = 0; ri < 4; ++ri) {
            int row = 4 * g + ri;
            __builtin_nontemporal_store(fmaxf(oa0[ri] + up0v, 0.f),
                                        &ctx[(size_t)row * CC + c0]);
            __builtin_nontemporal_store(fmaxf(oa1[ri] + up1v, 0.f),
                                        &ctx[(size_t)row * CC + c1]);
        }
    }
}

// ---------------------------------------------------------------------------
// Fallback (ws too small): round-2 validated self-contained kernel.
// ---------------------------------------------------------------------------
__global__ __launch_bounds__(256, 3) void fused_fallback(
    const float* __restrict__ tgt, const float* __restrict__ itc,
    const float* __restrict__ user, const int* __restrict__ mask,
    const float* __restrict__ wd, const float* __restrict__ bd,
    const float* __restrict__ Wm, const float* __restrict__ bm,
    float* __restrict__ out_ctx, float* __restrict__ out_attn) {
    __shared__ __align__(16) short Vt[CC][VTP];
    __shared__ __align__(16) float pool[IB][CC + 4];
    __shared__ __align__(16) float skv[JJ];
    __shared__ __align__(16) float stv[IB];
    __shared__ __align__(16) float upv[CC];
    __shared__ __align__(16) float dinv_lds[IB];
    __shared__ unsigned char mk[JJ];

    int b = blockIdx.x;
    int x = b & 7, q = b >> 3;
    int u = x + 8 * (q >> 4);
    int ib = q & 15;
    int i0 = ib * IB;
    int t = threadIdx.x;

    mk[t] = (unsigned char)(mask[u * JJ + t] != 0);
    mk[t + 256] = (unsigned char)(mask[u * JJ + t + 256] != 0);

    {
        int lane = t & 63, w4 = t >> 6;
        float2 w2 = *(const float2*)&wd[CC + lane * 2];
        for (int r = w4; r < JJ; r += 4) {
            float2 a = *(const float2*)&itc[((size_t)u * JJ + r) * CC + lane * 2];
            float s = wave_reduce_add(a.x * w2.x + a.y * w2.y);
            if (lane == 0) skv[r] = s;
        }
        float2 w1 = *(const float2*)&wd[lane * 2];
        float bdv = bd[0];
        for (int r = w4; r < IB; r += 4) {
            float2 a = *(const float2*)&tgt[((size_t)u * II + i0 + r) * CC + lane * 2];
            float s = wave_reduce_add(a.x * w1.x + a.y * w1.y);
            if (lane == 0) stv[r] = s + bdv;
        }
        if (t < CC) {
            float acc = bm[t];
            for (int e = 0; e < EE; ++e) acc += user[u * EE + e] * Wm[e * CC + t];
            upv[t] = acc;
        }
    }
    __syncthreads();

    const int l = t & 63;
    const int w = t >> 6;
    const int ln = l & 15;
    const int g = l >> 4;

    bf16x8 a[16];
    float rowsum = 0.0f;
    {
        float s = stv[ln];
#pragma unroll
        for (int t16 = 0; t16 < 16; ++t16) {
            int j = 32 * t16 + 8 * g;
            float4 k0 = *(const float4*)&skv[j];
            float4 k1 = *(const float4*)&skv[j + 4];
            unsigned m0 = *(const unsigned*)&mk[j];
            unsigned m1 = *(const unsigned*)&mk[j + 4];
            float pf[8];
            pf[0] = (m0 & 0x000000FFu) ? __expf(fast_tanh(s + k0.x)) : 0.0f;
            pf[1] = (m0 & 0x0000FF00u) ? __expf(fast_tanh(s + k0.y)) : 0.0f;
            pf[2] = (m0 & 0x00FF0000u) ? __expf(fast_tanh(s + k0.z)) : 0.0f;
            pf[3] = (m0 & 0xFF000000u) ? __expf(fast_tanh(s + k0.w)) : 0.0f;
            pf[4] = (m1 & 0x000000FFu) ? __expf(fast_tanh(s + k1.x)) : 0.0f;
            pf[5] = (m1 & 0x0000FF00u) ? __expf(fast_tanh(s + k1.y)) : 0.0f;
            pf[6] = (m1 & 0x00FF0000u) ? __expf(fast_tanh(s + k1.z)) : 0.0f;
            pf[7] = (m1 & 0xFF000000u) ? __expf(fast_tanh(s + k1.w)) : 0.0f;
            rowsum += pf[0] + pf[1] + pf[2] + pf[3] + pf[4] + pf[5] + pf[6] + pf[7];
            FragU cu;
            cu.u[0] = pack_bf16x2(pf[0], pf[1]);
            cu.u[1] = pack_bf16x2(pf[2], pf[3]);
            cu.u[2] = pack_bf16x2(pf[4], pf[5]);
            cu.u[3] = pack_bf16x2(pf[6], pf[7]);
            a[t16] = cu.v;
        }
    }
    rowsum += __shfl_xor(rowsum, 16, 64);
    rowsum += __shfl_xor(rowsum, 32, 64);
    float dinv = 1.0f / rowsum;
    if (t < 16) dinv_lds[t] = dinv;

    {
        float* abase = out_attn + ((size_t)(u * II + i0 + ln)) * JJ + 8 * g;
#pragma unroll
        for (int t16 = 0; t16 < 16; ++t16) {
            FragU cu; cu.v = a[t16];
            float f0 = __uint_as_float(cu.u[0] << 16) * dinv;
            float f1 = __uint_as_float(cu.u[0] & 0xFFFF0000u) * dinv;
            float f2 = __uint_as_float(cu.u[1] << 16) * dinv;
            float f3 = __uint_as_float(cu.u[1] & 0xFFFF0000u) * dinv;
            float f4 = __uint_as_float(cu.u[2] << 16) * dinv;
            float f5 = __uint_as_float(cu.u[2] & 0xFFFF0000u) * dinv;
            float f6 = __uint_as_float(cu.u[3] << 16) * dinv;
            float f7 = __uint_as_float(cu.u[3] & 0xFFFF0000u) * dinv;
            *(float4*)&abase[32 * t16] = make_float4(f0, f1, f2, f3);
            *(float4*)&abase[32 * t16 + 4] = make_float4(f4, f5, f6, f7);
        }
    }

    f32x4 acc0 = {0.f, 0.f, 0.f, 0.f};
    f32x4 acc1 = {0.f, 0.f, 0.f, 0.f};
    const float* Vu = itc + (size_t)u * JJ * CC;
    const int cg = t & 31;
    const int jp = t >> 5;
    const int n0 = w * 32;

    for (int jt = 0; jt < 8; ++jt) {
        int j0 = jt * JT;
        __syncthreads();
#pragma unroll
        for (int it = 0; it < 4; ++it) {
            int jl = 2 * (jp + 8 * it);
            const float* r0 = &Vu[(size_t)(j0 + jl) * CC];
            const float* r1 = r0 + CC;
#pragma unroll
            for (int qv = 0; qv < 4; ++qv) {
                int c = cg + 32 * qv;
                *(unsigned*)&Vt[c][jl] = pack_bf16x2(r0[c], r1[c]);
            }
        }
        __syncthreads();
#pragma unroll
        for (int kk = 0; kk < 2; ++kk) {
            bf16x8 b0 = *(const bf16x8*)&Vt[n0 + ln][32 * kk + 8 * g];
            bf16x8 b1 = *(const bf16x8*)&Vt[n0 + 16 + ln][32 * kk + 8 * g];
            acc0 = __builtin_amdgcn_mfma_f32_16x16x32_bf16(a[2 * jt + kk], b0,
                                                           acc0, 0, 0, 0);
            acc1 = __builtin_amdgcn_mfma_f32_16x16x32_bf16(a[2 * jt + kk], b1,
                                                           acc1, 0, 0, 0);
        }
    }

    __syncthreads();
    {
        float4 dv = *(const float4*)&dinv_lds[4 * g];
        float dvr[4] = {dv.x, dv.y, dv.z, dv.w};
#pragma unroll
        for (int r = 0; r < 4; ++r) {
            pool[4 * g + r][n0 + ln] = acc0[r] * dvr[r];
            pool[4 * g + r][n0 + 16 + ln] = acc1[r] * dvr[r];
        }
    }
    __syncthreads();

    {
        int tx = t & 15, ty = t >> 4;
        float o[8];
#pragma unroll
        for (int k = 0; k < 8; ++k) o[k] = 0.f;
#pragma unroll 4
        for (int k = 0; k < CC; ++k) {
            float pk = pool[ty][k];
            float4 w0 = *(const float4*)&Wm[(size_t)(EE + k) * CC + tx * 8];
            float4 w1 = *(const float4*)&Wm[(size_t)(EE + k) * CC + tx * 8 + 4];
            o[0] += pk * w0.x; o[1] += pk * w0.y; o[2] += pk * w0.z; o[3] += pk * w0.w;
            o[4] += pk * w1.x; o[5] += pk * w1.y; o[6] += pk * w1.z; o[7] += pk * w1.w;
        }
        float4 up0 = *(const float4*)&upv[tx * 8];
        float4 up1 = *(const float4*)&upv[tx * 8 + 4];
        float4 r0, r1;
        r0.x = fmaxf(o[0] + up0.x, 0.f); r0.y = fmaxf(o[1] + up0.y, 0.f);
        r0.z = fmaxf(o[2] + up0.z, 0.f); r0.w = fmaxf(o[3] + up0.w, 0.f);
        r1.x = fmaxf(o[4] + up1.x, 0.f); r1.y = fmaxf(o[5] + up1.y, 0.f);
        r1.z = fmaxf(o[6] + up1.z, 0.f); r1.w = fmaxf(o[7] + up1.w, 0.f);
        float* ctx = out_ctx + ((size_t)(u * II + i0 + ty)) * CC + tx * 8;
        *(float4*)&ctx[0] = r0;
        *(float4*)&ctx[4] = r1;
    }
}

// ---------------------------------------------------------------------------
extern "C" void kernel_launch(void* const* d_in, const int* in_sizes, int n_in,
                              void* d_out, int out_size, void* d_ws,
                              size_t ws_size, hipStream_t stream) {
    const float* tgt  = (const float*)d_in[0];
    const float* itc  = (const float*)d_in[1];
    const float* user = (const float*)d_in[2];
    const int*   mask = (const int*)d_in[3];
    const float* wd   = (const float*)d_in[4];
    const float* bd   = (const float*)d_in[5];
    const float* Wm   = (const float*)d_in[6];
    const float* bm   = (const float*)d_in[7];
    float* out_ctx  = (float*)d_out;
    float* out_attn = out_ctx + (size_t)UU * II * CC;

    size_t scalars = (size_t)(UU * JJ + UU * CC) * sizeof(float);
    size_t vt_bytes = (size_t)UU * NJT * 8192 * sizeof(short);
    size_t wt_bytes = (size_t)16384 * sizeof(short);
    size_t need = scalars + vt_bytes + wt_bytes;
    if (ws_size >= need) {
        float* sk_g = (float*)d_ws;
        float* up_g = sk_g + UU * JJ;
        short* vt_g = (short*)((char*)d_ws + scalars);
        short* wt_g = vt_g + (size_t)UU * NJT * 8192;
        int gridA = VT_BLOCKS + UP_BLOCKS + 1;
        precompute_kernel<<<gridA, 256, 0, stream>>>(itc, user, wd, Wm, bm,
                                                     sk_g, up_g, vt_g, wt_g);
        fused_main<<<UU * NIB, 256, 0, stream>>>(tgt, mask, wd, bd, sk_g, up_g,
                                                 vt_g, wt_g, out_ctx, out_attn);
    } else {
        fused_fallback<<<UU * NIB, 256, 0, stream>>>(
            tgt, itc, user, mask, wd, bd, Wm, bm, out_ctx, out_attn);
    }
}

// Round 8
// 58.064 us; speedup vs baseline: 1.0537x; 1.0537x over previous
//
#include <hip/hip_runtime.h>

// Problem constants (UserContextAttentionPooler): U=128, I=256, J=512, C=E=128
#define UU 128
#define II 256
#define JJ 512
#define CC 128
#define EE 128
#define IB 16            // i-rows per block
#define NIB 16           // i-tiles per u
#define JT 64            // j per V tile
#define NJT 8            // V tiles per u
#define VTP 72           // (fallback kernel) Vt row stride in shorts

typedef short bf16x8 __attribute__((ext_vector_type(8)));
typedef float f32x4 __attribute__((ext_vector_type(4)));

union FragU { bf16x8 v; unsigned u[4]; };

__device__ __forceinline__ float fast_tanh(float x) {
    float ex = __expf(2.0f * x);
    return 1.0f - 2.0f / (ex + 1.0f);
}

__device__ __forceinline__ unsigned pack_bf16x2(float lo, float hi) {
    unsigned ul = __float_as_uint(lo), uh = __float_as_uint(hi);
    ul = (ul + 0x7FFFu + ((ul >> 16) & 1u)) >> 16;
    uh = (uh + 0x7FFFu + ((uh >> 16) & 1u)) >> 16;
    return ul | (uh << 16);
}

__device__ __forceinline__ short bf16s(float f) {
    unsigned u = __float_as_uint(f);
    u = (u + 0x7FFFu + ((u >> 16) & 1u)) >> 16;
    return (short)u;
}

__device__ __forceinline__ float wave_reduce_add(float v) {
#pragma unroll
    for (int k = 32; k >= 1; k >>= 1) v += __shfl_xor(v, k, 64);
    return v;
}

// ---------------------------------------------------------------------------
// Kernel A: VT pass (vt_g bf16 B-tiles + s_k; itc read once, nontemporal;
// writer XCD == consumer XCD == u%8), u_part (U,C)[+b_mlp], wt_g = bf16
// W_mlp[E:] B-frags. Vt tile (u,jt), short idx: kk*4096 + c*32 + (j&31);
// a wave B-frag load is a contiguous 1KB region.
// ---------------------------------------------------------------------------
#define VT_BLOCKS (UU * NJT)      // 1024 (multiple of 8 at offset 0)
#define UP_BLOCKS (UU * CC / 256) // 64

__global__ void precompute_kernel(const float* __restrict__ itc,
                                  const float* __restrict__ user,
                                  const float* __restrict__ wd,
                                  const float* __restrict__ Wm,
                                  const float* __restrict__ bm,
                                  float* __restrict__ sk_g,
                                  float* __restrict__ up_g,
                                  short* __restrict__ vtg,
                                  short* __restrict__ wtg) {
    __shared__ float vt_f[JT][CC + 4];
    int b = blockIdx.x;
    int t = threadIdx.x;
    if (b < VT_BLOCKS) {
        int u = b & 127, jt = b >> 7;   // u fast -> writer XCD = u%8
        const float* src = itc + ((size_t)u * JJ + jt * JT) * CC;
#pragma unroll
        for (int k = 0; k < 8; ++k) {
            int f = t + 256 * k;
            int row = f >> 5, c4 = (f & 31) * 4;
            f32x4 v = __builtin_nontemporal_load(
                (const f32x4*)&src[(size_t)row * CC + c4]);
            *(f32x4*)&vt_f[row][c4] = v;
        }
        __syncthreads();
        // s_k for these 64 rows (4 threads per row)
        {
            int r = t >> 2, q4 = t & 3;
            float s = 0.f;
#pragma unroll
            for (int cc = 0; cc < 32; cc += 4) {
                float4 a = *(const float4*)&vt_f[r][q4 * 32 + cc];
                float4 w = *(const float4*)&wd[CC + q4 * 32 + cc];
                s += a.x * w.x + a.y * w.y + a.z * w.z + a.w * w.w;
            }
            s += __shfl_xor(s, 1, 64);
            s += __shfl_xor(s, 2, 64);
            if (q4 == 0) sk_g[u * JJ + jt * JT + r] = s;
        }
        // pack transposed bf16 tile: [kk][c][j&31], 16B stores
        {
            int c = t & 127, half = t >> 7;
            unsigned* dst = (unsigned*)(vtg + (size_t)(u * NJT + jt) * 8192) +
                            half * 2048 + c * 16;
#pragma unroll
            for (int m4 = 0; m4 < 4; ++m4) {
                unsigned q[4];
#pragma unroll
                for (int mm = 0; mm < 4; ++mm) {
                    int m = 4 * m4 + mm;
                    q[mm] = pack_bf16x2(vt_f[32 * half + 2 * m][c],
                                        vt_f[32 * half + 2 * m + 1][c]);
                }
                *(uint4*)&dst[4 * m4] = make_uint4(q[0], q[1], q[2], q[3]);
            }
        }
    } else if (b < VT_BLOCKS + UP_BLOCKS) {
        int idx = (b - VT_BLOCKS) * 256 + t;
        int u = idx >> 7, c = idx & 127;
        float acc = bm[c];
#pragma unroll 8
        for (int e = 0; e < EE; ++e) acc += user[u * EE + e] * Wm[e * CC + c];
        up_g[idx] = acc;
    } else {
        // pack W_mlp[E:] (128x128) -> wt_g, B-frag order
        int n = t & 127, khalf = t >> 7;
#pragma unroll
        for (int ks2 = 0; ks2 < 2; ++ks2) {
            int ks = khalf * 2 + ks2;
#pragma unroll
            for (int g = 0; g < 4; ++g) {
                unsigned q[4];
#pragma unroll
                for (int pr = 0; pr < 4; ++pr) {
                    float lo = Wm[(size_t)(EE + 32 * ks + 8 * g + 2 * pr) * CC + n];
                    float hi = Wm[(size_t)(EE + 32 * ks + 8 * g + 2 * pr + 1) * CC + n];
                    q[pr] = pack_bf16x2(lo, hi);
                }
                *(uint4*)&wtg[ks * 4096 + n * 32 + 8 * g] =
                    make_uint4(q[0], q[1], q[2], q[3]);
            }
        }
    }
}

// ---------------------------------------------------------------------------
// Kernel B (main): one block per (u, 16-row i-tile), 256 threads = 4 waves,
// 6 blocks/CU (reg-dieted: attn values re-read from ps LDS, B-prefetch depth
// 8 frags rolling). Loads issued before attn stores in VMEM order.
// ---------------------------------------------------------------------------
__global__ __launch_bounds__(256, 6) void fused_main(
    const float* __restrict__ tgt, const int* __restrict__ mask,
    const float* __restrict__ wd, const float* __restrict__ bd,
    const float* __restrict__ sk_g, const float* __restrict__ up_g,
    const short* __restrict__ vt_g, const short* __restrict__ wt_g,
    float* __restrict__ out_ctx, float* __restrict__ out_attn) {
    __shared__ __align__(16) short ps[8192];       // 16KB p tile (swizzled)
    __shared__ __align__(16) short pooled_bf[2048];// 4KB pooled tile (swizzled)
    __shared__ float dinv_lds[IB];

    int b = blockIdx.x;
    int x = b & 7, qq = b >> 3;
    int u = x + 8 * (qq >> 4);     // 16 blocks of a given u -> same XCD
    int ib = qq & 15;
    int i0 = ib * IB;
    int t = threadIdx.x;
    int w = t >> 6, l = t & 63, ln = l & 15, g = l >> 4;
    int r = t >> 4, s4 = t & 15;

    // ---- Phase 0: s_t in-block (row r, 16 threads per row; nt stream) ----
    float sv;
    {
        const float* trow = tgt + ((size_t)(u * II + i0 + r)) * CC + s4 * 8;
        f32x4 t0 = __builtin_nontemporal_load((const f32x4*)&trow[0]);
        f32x4 t1 = __builtin_nontemporal_load((const f32x4*)&trow[4]);
        float4 w0 = *(const float4*)&wd[s4 * 8];
        float4 w1 = *(const float4*)&wd[s4 * 8 + 4];
        float part = t0[0] * w0.x + t0[1] * w0.y + t0[2] * w0.z + t0[3] * w0.w +
                     t1[0] * w1.x + t1[1] * w1.y + t1[2] * w1.z + t1[3] * w1.w;
        part += __shfl_xor(part, 1, 64);
        part += __shfl_xor(part, 2, 64);
        part += __shfl_xor(part, 4, 64);
        part += __shfl_xor(part, 8, 64);
        sv = part + bd[0];
    }

    // ---- Phase 1: p once per block; 32 elems/thread -> swizzled ps LDS ----
    const float* skb = sk_g + u * JJ;
    const int* mkb = mask + u * JJ;
    float rowsum = 0.f;
#pragma unroll
    for (int h = 0; h < 4; ++h) {
        int jb = 8 * (s4 + 16 * h);
        float4 k0 = *(const float4*)&skb[jb];
        float4 k1 = *(const float4*)&skb[jb + 4];
        int4 m0 = *(const int4*)&mkb[jb];
        int4 m1 = *(const int4*)&mkb[jb + 4];
        float p0 = m0.x ? __expf(fast_tanh(sv + k0.x)) : 0.f;
        float p1 = m0.y ? __expf(fast_tanh(sv + k0.y)) : 0.f;
        float p2 = m0.z ? __expf(fast_tanh(sv + k0.z)) : 0.f;
        float p3 = m0.w ? __expf(fast_tanh(sv + k0.w)) : 0.f;
        float p4 = m1.x ? __expf(fast_tanh(sv + k1.x)) : 0.f;
        float p5 = m1.y ? __expf(fast_tanh(sv + k1.y)) : 0.f;
        float p6 = m1.z ? __expf(fast_tanh(sv + k1.z)) : 0.f;
        float p7 = m1.w ? __expf(fast_tanh(sv + k1.w)) : 0.f;
        rowsum += p0 + p1 + p2 + p3 + p4 + p5 + p6 + p7;
        unsigned q0 = pack_bf16x2(p0, p1);
        unsigned q1 = pack_bf16x2(p2, p3);
        unsigned q2 = pack_bf16x2(p4, p5);
        unsigned q3 = pack_bf16x2(p6, p7);
        int gp = (s4 + 16 * h) ^ (r & 7);
        *(uint4*)((char*)ps + r * 1024 + 16 * gp) = make_uint4(q0, q1, q2, q3);
    }
    rowsum += __shfl_xor(rowsum, 1, 64);
    rowsum += __shfl_xor(rowsum, 2, 64);
    rowsum += __shfl_xor(rowsum, 4, 64);
    rowsum += __shfl_xor(rowsum, 8, 64);
    float dinv = 1.0f / rowsum;
    if (s4 == 0) dinv_lds[r] = dinv;

    // ---- Phase 3 prefetch FIRST (loads ahead of stores in VMEM queue) ----
    // rolling depth 4 steps (8 frags, 32 VGPR)
    const short* b_base =
        vt_g + (size_t)u * (NJT * 8192) + (32 * w + ln) * 32 + 8 * g;
    bf16x8 pb0[4], pb1[4];
#pragma unroll
    for (int s = 0; s < 4; ++s) {
        int off = (s >> 1) * 8192 + (s & 1) * 4096;
        pb0[s] = *(const bf16x8*)&b_base[off];
        pb1[s] = *(const bf16x8*)&b_base[off + 512];
    }

    // ---- Phase 2: attn = bf16(p)*dinv; values re-read from own ps granules
    //      (no persistent pk registers), nontemporal stores ----
    {
        float* ab = out_attn + ((size_t)(u * II + i0 + r)) * JJ;
#pragma unroll
        for (int h = 0; h < 4; ++h) {
            int gp = (s4 + 16 * h) ^ (r & 7);
            uint4 q = *(const uint4*)((char*)ps + r * 1024 + 16 * gp);
            int jb = 8 * (s4 + 16 * h);
            f32x4 v0, v1;
            v0[0] = __uint_as_float(q.x << 16) * dinv;
            v0[1] = __uint_as_float(q.x & 0xFFFF0000u) * dinv;
            v0[2] = __uint_as_float(q.y << 16) * dinv;
            v0[3] = __uint_as_float(q.y & 0xFFFF0000u) * dinv;
            v1[0] = __uint_as_float(q.z << 16) * dinv;
            v1[1] = __uint_as_float(q.z & 0xFFFF0000u) * dinv;
            v1[2] = __uint_as_float(q.w << 16) * dinv;
            v1[3] = __uint_as_float(q.w & 0xFFFF0000u) * dinv;
            __builtin_nontemporal_store(v0, (f32x4*)&ab[jb]);
            __builtin_nontemporal_store(v1, (f32x4*)&ab[jb + 4]);
        }
    }

    // LDS-only barrier (no vmcnt drain: stores + prefetch stay in flight)
    asm volatile("s_waitcnt lgkmcnt(0)" ::: "memory");
    __builtin_amdgcn_s_barrier();
    asm volatile("" ::: "memory");

    // ---- Phase 3: 16 MFMA steps, rolling 4-step register pipeline ----
    f32x4 acc0 = {0.f, 0.f, 0.f, 0.f};
    f32x4 acc1 = {0.f, 0.f, 0.f, 0.f};
    __builtin_amdgcn_s_setprio(1);
#pragma unroll
    for (int s = 0; s < 16; ++s) {
        bf16x8 af = *(const bf16x8*)((const char*)ps + ln * 1024 +
                                     16 * ((4 * s + g) ^ (ln & 7)));
        acc0 = __builtin_amdgcn_mfma_f32_16x16x32_bf16(af, pb0[s & 3], acc0, 0, 0, 0);
        acc1 = __builtin_amdgcn_mfma_f32_16x16x32_bf16(af, pb1[s & 3], acc1, 0, 0, 0);
        if (s < 12) {
            int off = ((s + 4) >> 1) * 8192 + ((s + 4) & 1) * 4096;
            pb0[s & 3] = *(const bf16x8*)&b_base[off];
            pb1[s & 3] = *(const bf16x8*)&b_base[off + 512];
        }
    }
    __builtin_amdgcn_s_setprio(0);

    // ---- Phase 5 W-frag prefetch (L2-hot 32KB, shared by all blocks) ----
    const short* wbase = wt_g + (32 * w + ln) * 32 + 8 * g;
    bf16x8 wb0[4], wb1[4];
#pragma unroll
    for (int ks = 0; ks < 4; ++ks) {
        wb0[ks] = *(const bf16x8*)&wbase[ks * 4096];
        wb1[ks] = *(const bf16x8*)&wbase[ks * 4096 + 512];
    }

    // ---- Phase 4: scale pooled by dinv, pack bf16 -> swizzled LDS ----
#pragma unroll
    for (int ri = 0; ri < 4; ++ri) {
        int row = 4 * g + ri;
        float dv = dinv_lds[row];
        int c0 = 32 * w + ln;
        int by0 = row * 256 + 16 * ((c0 >> 3) ^ (row & 7)) + 2 * (ln & 7);
        *(short*)((char*)pooled_bf + by0) = bf16s(acc0[ri] * dv);
        int c1 = c0 + 16;
        int by1 = row * 256 + 16 * ((c1 >> 3) ^ (row & 7)) + 2 * (ln & 7);
        *(short*)((char*)pooled_bf + by1) = bf16s(acc1[ri] * dv);
    }
    asm volatile("s_waitcnt lgkmcnt(0)" ::: "memory");
    __builtin_amdgcn_s_barrier();
    asm volatile("" ::: "memory");

    // ---- Phase 5: out = relu(u_part + pooled @ W_mlp[E:]) via MFMA ----
    f32x4 oa0 = {0.f, 0.f, 0.f, 0.f};
    f32x4 oa1 = {0.f, 0.f, 0.f, 0.f};
#pragma unroll
    for (int ks = 0; ks < 4; ++ks) {
        bf16x8 pa = *(const bf16x8*)((const char*)pooled_bf + ln * 256 +
                                     16 * ((4 * ks + g) ^ (ln & 7)));
        oa0 = __builtin_amdgcn_mfma_f32_16x16x32_bf16(pa, wb0[ks], oa0, 0, 0, 0);
        oa1 = __builtin_amdgcn_mfma_f32_16x16x32_bf16(pa, wb1[ks], oa1, 0, 0, 0);
    }
    {
        int c0 = 32 * w + ln, c1 = c0 + 16;
        float up0v = up_g[u * CC + c0];
        float up1v = up_g[u * CC + c1];
        float* ctx = out_ctx + ((size_t)(u * II + i0)) * CC;
#pragma unroll
        for (int ri = 0; ri < 4; ++ri) {
            int row = 4 * g + ri;
            __builtin_nontemporal_store(fmaxf(oa0[ri] + up0v, 0.f),
                                        &ctx[(size_t)row * CC + c0]);
            __builtin_nontemporal_store(fmaxf(oa1[ri] + up1v, 0.f),
                                        &ctx[(size_t)row * CC + c1]);
        }
    }
}

// ---------------------------------------------------------------------------
// Fallback (ws too small): round-2 validated self-contained kernel.
// ---------------------------------------------------------------------------
__global__ __launch_bounds__(256, 3) void fused_fallback(
    const float* __restrict__ tgt, const float* __restrict__ itc,
    const float* __restrict__ user, const int* __restrict__ mask,
    const float* __restrict__ wd, const float* __restrict__ bd,
    const float* __restrict__ Wm, const float* __restrict__ bm,
    float* __restrict__ out_ctx, float* __restrict__ out_attn) {
    __shared__ __align__(16) short Vt[CC][VTP];
    __shared__ __align__(16) float pool[IB][CC + 4];
    __shared__ __align__(16) float skv[JJ];
    __shared__ __align__(16) float stv[IB];
    __shared__ __align__(16) float upv[CC];
    __shared__ __align__(16) float dinv_lds[IB];
    __shared__ unsigned char mk[JJ];

    int b = blockIdx.x;
    int x = b & 7, q = b >> 3;
    int u = x + 8 * (q >> 4);
    int ib = q & 15;
    int i0 = ib * IB;
    int t = threadIdx.x;

    mk[t] = (unsigned char)(mask[u * JJ + t] != 0);
    mk[t + 256] = (unsigned char)(mask[u * JJ + t + 256] != 0);

    {
        int lane = t & 63, w4 = t >> 6;
        float2 w2 = *(const float2*)&wd[CC + lane * 2];
        for (int r = w4; r < JJ; r += 4) {
            float2 a = *(const float2*)&itc[((size_t)u * JJ + r) * CC + lane * 2];
            float s = wave_reduce_add(a.x * w2.x + a.y * w2.y);
            if (lane == 0) skv[r] = s;
        }
        float2 w1 = *(const float2*)&wd[lane * 2];
        float bdv = bd[0];
        for (int r = w4; r < IB; r += 4) {
            float2 a = *(const float2*)&tgt[((size_t)u * II + i0 + r) * CC + lane * 2];
            float s = wave_reduce_add(a.x * w1.x + a.y * w1.y);
            if (lane == 0) stv[r] = s + bdv;
        }
        if (t < CC) {
            float acc = bm[t];
            for (int e = 0; e < EE; ++e) acc += user[u * EE + e] * Wm[e * CC + t];
            upv[t] = acc;
        }
    }
    __syncthreads();

    const int l = t & 63;
    const int w = t >> 6;
    const int ln = l & 15;
    const int g = l >> 4;

    bf16x8 a[16];
    float rowsum = 0.0f;
    {
        float s = stv[ln];
#pragma unroll
        for (int t16 = 0; t16 < 16; ++t16) {
            int j = 32 * t16 + 8 * g;
            float4 k0 = *(const float4*)&skv[j];
            float4 k1 = *(const float4*)&skv[j + 4];
            unsigned m0 = *(const unsigned*)&mk[j];
            unsigned m1 = *(const unsigned*)&mk[j + 4];
            float pf[8];
            pf[0] = (m0 & 0x000000FFu) ? __expf(fast_tanh(s + k0.x)) : 0.0f;
            pf[1] = (m0 & 0x0000FF00u) ? __expf(fast_tanh(s + k0.y)) : 0.0f;
            pf[2] = (m0 & 0x00FF0000u) ? __expf(fast_tanh(s + k0.z)) : 0.0f;
            pf[3] = (m0 & 0xFF000000u) ? __expf(fast_tanh(s + k0.w)) : 0.0f;
            pf[4] = (m1 & 0x000000FFu) ? __expf(fast_tanh(s + k1.x)) : 0.0f;
            pf[5] = (m1 & 0x0000FF00u) ? __expf(fast_tanh(s + k1.y)) : 0.0f;
            pf[6] = (m1 & 0x00FF0000u) ? __expf(fast_tanh(s + k1.z)) : 0.0f;
            pf[7] = (m1 & 0xFF000000u) ? __expf(fast_tanh(s + k1.w)) : 0.0f;
            rowsum += pf[0] + pf[1] + pf[2] + pf[3] + pf[4] + pf[5] + pf[6] + pf[7];
            FragU cu;
            cu.u[0] = pack_bf16x2(pf[0], pf[1]);
            cu.u[1] = pack_bf16x2(pf[2], pf[3]);
            cu.u[2] = pack_bf16x2(pf[4], pf[5]);
            cu.u[3] = pack_bf16x2(pf[6], pf[7]);
            a[t16] = cu.v;
        }
    }
    rowsum += __shfl_xor(rowsum, 16, 64);
    rowsum += __shfl_xor(rowsum, 32, 64);
    float dinv = 1.0f / rowsum;
    if (t < 16) dinv_lds[t] = dinv;

    {
        float* abase = out_attn + ((size_t)(u * II + i0 + ln)) * JJ + 8 * g;
#pragma unroll
        for (int t16 = 0; t16 < 16; ++t16) {
            FragU cu; cu.v = a[t16];
            float f0 = __uint_as_float(cu.u[0] << 16) * dinv;
            float f1 = __uint_as_float(cu.u[0] & 0xFFFF0000u) * dinv;
            float f2 = __uint_as_float(cu.u[1] << 16) * dinv;
            float f3 = __uint_as_float(cu.u[1] & 0xFFFF0000u) * dinv;
            float f4 = __uint_as_float(cu.u[2] << 16) * dinv;
            float f5 = __uint_as_float(cu.u[2] & 0xFFFF0000u) * dinv;
            float f6 = __uint_as_float(cu.u[3] << 16) * dinv;
            float f7 = __uint_as_float(cu.u[3] & 0xFFFF0000u) * dinv;
            *(float4*)&abase[32 * t16] = make_float4(f0, f1, f2, f3);
            *(float4*)&abase[32 * t16 + 4] = make_float4(f4, f5, f6, f7);
        }
    }

    f32x4 acc0 = {0.f, 0.f, 0.f, 0.f};
    f32x4 acc1 = {0.f, 0.f, 0.f, 0.f};
    const float* Vu = itc + (size_t)u * JJ * CC;
    const int cg = t & 31;
    const int jp = t >> 5;
    const int n0 = w * 32;

    for (int jt = 0; jt < 8; ++jt) {
        int j0 = jt * JT;
        __syncthreads();
#pragma unroll
        for (int it = 0; it < 4; ++it) {
            int jl = 2 * (jp + 8 * it);
            const float* r0 = &Vu[(size_t)(j0 + jl) * CC];
            const float* r1 = r0 + CC;
#pragma unroll
            for (int qv = 0; qv < 4; ++qv) {
                int c = cg + 32 * qv;
                *(unsigned*)&Vt[c][jl] = pack_bf16x2(r0[c], r1[c]);
            }
        }
        __syncthreads();
#pragma unroll
        for (int kk = 0; kk < 2; ++kk) {
            bf16x8 b0 = *(const bf16x8*)&Vt[n0 + ln][32 * kk + 8 * g];
            bf16x8 b1 = *(const bf16x8*)&Vt[n0 + 16 + ln][32 * kk + 8 * g];
            acc0 = __builtin_amdgcn_mfma_f32_16x16x32_bf16(a[2 * jt + kk], b0,
                                                           acc0, 0, 0, 0);
            acc1 = __builtin_amdgcn_mfma_f32_16x16x32_bf16(a[2 * jt + kk], b1,
                                                           acc1, 0, 0, 0);
        }
    }

    __syncthreads();
    {
        float4 dv = *(const float4*)&dinv_lds[4 * g];
        float dvr[4] = {dv.x, dv.y, dv.z, dv.w};
#pragma unroll
        for (int r = 0; r < 4; ++r) {
            pool[4 * g + r][n0 + ln] = acc0[r] * dvr[r];
            pool[4 * g + r][n0 + 16 + ln] = acc1[r] * dvr[r];
        }
    }
    __syncthreads();

    {
        int tx = t & 15, ty = t >> 4;
        float o[8];
#pragma unroll
        for (int k = 0; k < 8; ++k) o[k] = 0.f;
#pragma unroll 4
        for (int k = 0; k < CC; ++k) {
            float pk = pool[ty][k];
            float4 w0 = *(const float4*)&Wm[(size_t)(EE + k) * CC + tx * 8];
            float4 w1 = *(const float4*)&Wm[(size_t)(EE + k) * CC + tx * 8 + 4];
            o[0] += pk * w0.x; o[1] += pk * w0.y; o[2] += pk * w0.z; o[3] += pk * w0.w;
            o[4] += pk * w1.x; o[5] += pk * w1.y; o[6] += pk * w1.z; o[7] += pk * w1.w;
        }
        float4 up0 = *(const float4*)&upv[tx * 8];
        float4 up1 = *(const float4*)&upv[tx * 8 + 4];
        float4 r0, r1;
        r0.x = fmaxf(o[0] + up0.x, 0.f); r0.y = fmaxf(o[1] + up0.y, 0.f);
        r0.z = fmaxf(o[2] + up0.z, 0.f); r0.w = fmaxf(o[3] + up0.w, 0.f);
        r1.x = fmaxf(o[4] + up1.x, 0.f); r1.y = fmaxf(o[5] + up1.y, 0.f);
        r1.z = fmaxf(o[6] + up1.z, 0.f); r1.w = fmaxf(o[7] + up1.w, 0.f);
        float* ctx = out_ctx + ((size_t)(u * II + i0 + ty)) * CC + tx * 8;
        *(float4*)&ctx[0] = r0;
        *(float4*)&ctx[4] = r1;
    }
}

// ---------------------------------------------------------------------------
extern "C" void kernel_launch(void* const* d_in, const int* in_sizes, int n_in,
                              void* d_out, int out_size, void* d_ws,
                              size_t ws_size, hipStream_t stream) {
    const float* tgt  = (const float*)d_in[0];
    const float* itc  = (const float*)d_in[1];
    const float* user = (const float*)d_in[2];
    const int*   mask = (const int*)d_in[3];
    const float* wd   = (const float*)d_in[4];
    const float* bd   = (const float*)d_in[5];
    const float* Wm   = (const float*)d_in[6];
    const float* bm   = (const float*)d_in[7];
    float* out_ctx  = (float*)d_out;
    float* out_attn = out_ctx + (size_t)UU * II * CC;

    size_t scalars = (size_t)(UU * JJ + UU * CC) * sizeof(float);
    size_t vt_bytes = (size_t)UU * NJT * 8192 * sizeof(short);
    size_t wt_bytes = (size_t)16384 * sizeof(short);
    size_t need = scalars + vt_bytes + wt_bytes;
    if (ws_size >= need) {
        float* sk_g = (float*)d_ws;
        float* up_g = sk_g + UU * JJ;
        short* vt_g = (short*)((char*)d_ws + scalars);
        short* wt_g = vt_g + (size_t)UU * NJT * 8192;
        int gridA = VT_BLOCKS + UP_BLOCKS + 1;
        precompute_kernel<<<gridA, 256, 0, stream>>>(itc, user, wd, Wm, bm,
                                                     sk_g, up_g, vt_g, wt_g);
        fused_main<<<UU * NIB, 256, 0, stream>>>(tgt, mask, wd, bd, sk_g, up_g,
                                                 vt_g, wt_g, out_ctx, out_attn);
    } else {
        fused_fallback<<<UU * NIB, 256, 0, stream>>>(
            tgt, itc, user, mask, wd, bd, Wm, bm, out_ctx, out_attn);
    }
}

// Round 9
// 49.507 us; speedup vs baseline: 1.2358x; 1.1728x over previous
//
#include <hip/hip_runtime.h>

// Problem constants (UserContextAttentionPooler): U=128, I=256, J=512, C=E=128
#define UU 128
#define II 256
#define JJ 512
#define CC 128
#define EE 128
#define IB2 32           // i-rows per block (2 MFMA tiles)
#define NIB2 8           // i-blocks per u
#define JT 64            // j per V tile
#define NJT 8            // V tiles per u
#define VTP 72           // (fallback kernel) Vt row stride in shorts
#define IBF 16           // fallback i-rows per block

typedef short bf16x8 __attribute__((ext_vector_type(8)));
typedef float f32x4 __attribute__((ext_vector_type(4)));

union FragU { bf16x8 v; unsigned u[4]; };

__device__ __forceinline__ float fast_tanh(float x) {
    float ex = __expf(2.0f * x);
    return 1.0f - 2.0f / (ex + 1.0f);
}

__device__ __forceinline__ unsigned pack_bf16x2(float lo, float hi) {
    unsigned ul = __float_as_uint(lo), uh = __float_as_uint(hi);
    ul = (ul + 0x7FFFu + ((ul >> 16) & 1u)) >> 16;
    uh = (uh + 0x7FFFu + ((uh >> 16) & 1u)) >> 16;
    return ul | (uh << 16);
}

__device__ __forceinline__ short bf16s(float f) {
    unsigned u = __float_as_uint(f);
    u = (u + 0x7FFFu + ((u >> 16) & 1u)) >> 16;
    return (short)u;
}

__device__ __forceinline__ float wave_reduce_add(float v) {
#pragma unroll
    for (int k = 32; k >= 1; k >>= 1) v += __shfl_xor(v, k, 64);
    return v;
}

// ---------------------------------------------------------------------------
// Kernel A: VT pass (vt_g bf16 B-tiles + s_k; itc read once, nontemporal;
// writer XCD == consumer XCD == u%8), u_part (U,C)[+b_mlp], wt_g = bf16
// W_mlp[E:] B-frags. Vt tile (u,jt), short idx: kk*4096 + c*32 + (j&31);
// a wave B-frag load is a contiguous 1KB region.
// ---------------------------------------------------------------------------
#define VT_BLOCKS (UU * NJT)      // 1024 (multiple of 8 at offset 0)
#define UP_BLOCKS (UU * CC / 256) // 64

__global__ void precompute_kernel(const float* __restrict__ itc,
                                  const float* __restrict__ user,
                                  const float* __restrict__ wd,
                                  const float* __restrict__ Wm,
                                  const float* __restrict__ bm,
                                  float* __restrict__ sk_g,
                                  float* __restrict__ up_g,
                                  short* __restrict__ vtg,
                                  short* __restrict__ wtg) {
    __shared__ float vt_f[JT][CC + 4];
    int b = blockIdx.x;
    int t = threadIdx.x;
    if (b < VT_BLOCKS) {
        int u = b & 127, jt = b >> 7;   // u fast -> writer XCD = u%8
        const float* src = itc + ((size_t)u * JJ + jt * JT) * CC;
#pragma unroll
        for (int k = 0; k < 8; ++k) {
            int f = t + 256 * k;
            int row = f >> 5, c4 = (f & 31) * 4;
            f32x4 v = __builtin_nontemporal_load(
                (const f32x4*)&src[(size_t)row * CC + c4]);
            *(f32x4*)&vt_f[row][c4] = v;
        }
        __syncthreads();
        // s_k for these 64 rows (4 threads per row)
        {
            int r = t >> 2, q4 = t & 3;
            float s = 0.f;
#pragma unroll
            for (int cc = 0; cc < 32; cc += 4) {
                float4 a = *(const float4*)&vt_f[r][q4 * 32 + cc];
                float4 w = *(const float4*)&wd[CC + q4 * 32 + cc];
                s += a.x * w.x + a.y * w.y + a.z * w.z + a.w * w.w;
            }
            s += __shfl_xor(s, 1, 64);
            s += __shfl_xor(s, 2, 64);
            if (q4 == 0) sk_g[u * JJ + jt * JT + r] = s;
        }
        // pack transposed bf16 tile: [kk][c][j&31], 16B stores
        {
            int c = t & 127, half = t >> 7;
            unsigned* dst = (unsigned*)(vtg + (size_t)(u * NJT + jt) * 8192) +
                            half * 2048 + c * 16;
#pragma unroll
            for (int m4 = 0; m4 < 4; ++m4) {
                unsigned q[4];
#pragma unroll
                for (int mm = 0; mm < 4; ++mm) {
                    int m = 4 * m4 + mm;
                    q[mm] = pack_bf16x2(vt_f[32 * half + 2 * m][c],
                                        vt_f[32 * half + 2 * m + 1][c]);
                }
                *(uint4*)&dst[4 * m4] = make_uint4(q[0], q[1], q[2], q[3]);
            }
        }
    } else if (b < VT_BLOCKS + UP_BLOCKS) {
        int idx = (b - VT_BLOCKS) * 256 + t;
        int u = idx >> 7, c = idx & 127;
        float acc = bm[c];
#pragma unroll 8
        for (int e = 0; e < EE; ++e) acc += user[u * EE + e] * Wm[e * CC + c];
        up_g[idx] = acc;
    } else {
        // pack W_mlp[E:] (128x128) -> wt_g, B-frag order
        int n = t & 127, khalf = t >> 7;
#pragma unroll
        for (int ks2 = 0; ks2 < 2; ++ks2) {
            int ks = khalf * 2 + ks2;
#pragma unroll
            for (int g = 0; g < 4; ++g) {
                unsigned q[4];
#pragma unroll
                for (int pr = 0; pr < 4; ++pr) {
                    float lo = Wm[(size_t)(EE + 32 * ks + 8 * g + 2 * pr) * CC + n];
                    float hi = Wm[(size_t)(EE + 32 * ks + 8 * g + 2 * pr + 1) * CC + n];
                    q[pr] = pack_bf16x2(lo, hi);
                }
                *(uint4*)&wtg[ks * 4096 + n * 32 + 8 * g] =
                    make_uint4(q[0], q[1], q[2], q[3]);
            }
        }
    }
}

// ---------------------------------------------------------------------------
// Kernel B (main): one block per (u, 32-row i-slab) = 2 MFMA tiles sharing
// each B-fragment (halves vt_g feed traffic). 256 threads = 4 waves,
// 4 blocks/CU. Attn stores AFTER the MFMA phase (no stores ahead of B-refills
// in the vmcnt queue), perfectly coalesced via flat re-read of ps LDS.
// pooled tile overlays ps.
// ---------------------------------------------------------------------------
__global__ __launch_bounds__(256, 4) void fused_main(
    const float* __restrict__ tgt, const int* __restrict__ mask,
    const float* __restrict__ wd, const float* __restrict__ bd,
    const float* __restrict__ sk_g, const float* __restrict__ up_g,
    const short* __restrict__ vt_g, const short* __restrict__ wt_g,
    float* __restrict__ out_ctx, float* __restrict__ out_attn) {
    __shared__ __align__(16) short ps[16384];  // 32KB: 2 swizzled p tiles
    __shared__ float dinv_lds[IB2];

    int b = blockIdx.x;
    int x = b & 7, q = b >> 3;
    int u = x + 8 * (q >> 3);      // 8 blocks of a given u -> same XCD
    int ib = q & 7;
    int i0 = ib * IB2;
    int t = threadIdx.x;
    int w = t >> 6, l = t & 63, ln = l & 15, g = l >> 4;
    int r2 = t >> 3, seg8 = t & 7;  // phase0/1: row [0,32), col-segment [0,8)
    int tile = r2 >> 4, rr = r2 & 15;

    // ---- Phase 0: s_t for row r2 (8 threads/row, 16 floats each; nt) ----
    float sv;
    {
        const float* trow = tgt + ((size_t)(u * II + i0 + r2)) * CC + seg8 * 16;
        f32x4 t0 = __builtin_nontemporal_load((const f32x4*)&trow[0]);
        f32x4 t1 = __builtin_nontemporal_load((const f32x4*)&trow[4]);
        f32x4 t2 = __builtin_nontemporal_load((const f32x4*)&trow[8]);
        f32x4 t3 = __builtin_nontemporal_load((const f32x4*)&trow[12]);
        float4 w0 = *(const float4*)&wd[seg8 * 16];
        float4 w1 = *(const float4*)&wd[seg8 * 16 + 4];
        float4 w2 = *(const float4*)&wd[seg8 * 16 + 8];
        float4 w3 = *(const float4*)&wd[seg8 * 16 + 12];
        float part = t0[0] * w0.x + t0[1] * w0.y + t0[2] * w0.z + t0[3] * w0.w +
                     t1[0] * w1.x + t1[1] * w1.y + t1[2] * w1.z + t1[3] * w1.w +
                     t2[0] * w2.x + t2[1] * w2.y + t2[2] * w2.z + t2[3] * w2.w +
                     t3[0] * w3.x + t3[1] * w3.y + t3[2] * w3.z + t3[3] * w3.w;
        part += __shfl_xor(part, 1, 64);
        part += __shfl_xor(part, 2, 64);
        part += __shfl_xor(part, 4, 64);
        sv = part + bd[0];
    }

    // ---- Phase 1: p; thread handles 64 elems of row r2 (granules seg8+8h) ----
    const float* skb = sk_g + u * JJ;
    const int* mkb = mask + u * JJ;
    char* psrow = (char*)ps + tile * 16384 + rr * 1024;
    float rowsum = 0.f;
#pragma unroll 4
    for (int h = 0; h < 8; ++h) {
        int gcol = seg8 + 8 * h;
        int jb = gcol * 8;
        float4 k0 = *(const float4*)&skb[jb];
        float4 k1 = *(const float4*)&skb[jb + 4];
        int4 m0 = *(const int4*)&mkb[jb];
        int4 m1 = *(const int4*)&mkb[jb + 4];
        float p0 = m0.x ? __expf(fast_tanh(sv + k0.x)) : 0.f;
        float p1 = m0.y ? __expf(fast_tanh(sv + k0.y)) : 0.f;
        float p2 = m0.z ? __expf(fast_tanh(sv + k0.z)) : 0.f;
        float p3 = m0.w ? __expf(fast_tanh(sv + k0.w)) : 0.f;
        float p4 = m1.x ? __expf(fast_tanh(sv + k1.x)) : 0.f;
        float p5 = m1.y ? __expf(fast_tanh(sv + k1.y)) : 0.f;
        float p6 = m1.z ? __expf(fast_tanh(sv + k1.z)) : 0.f;
        float p7 = m1.w ? __expf(fast_tanh(sv + k1.w)) : 0.f;
        rowsum += p0 + p1 + p2 + p3 + p4 + p5 + p6 + p7;
        unsigned q0 = pack_bf16x2(p0, p1);
        unsigned q1 = pack_bf16x2(p2, p3);
        unsigned q2 = pack_bf16x2(p4, p5);
        unsigned q3 = pack_bf16x2(p6, p7);
        int gp = gcol ^ (rr & 7);
        *(uint4*)(psrow + 16 * gp) = make_uint4(q0, q1, q2, q3);
    }
    rowsum += __shfl_xor(rowsum, 1, 64);
    rowsum += __shfl_xor(rowsum, 2, 64);
    rowsum += __shfl_xor(rowsum, 4, 64);
    if (seg8 == 0) dinv_lds[r2] = 1.0f / rowsum;

    // ---- B prefetch (only loads in the VMEM queue; no stores ahead) ----
    const short* b_base =
        vt_g + (size_t)u * (NJT * 8192) + (32 * w + ln) * 32 + 8 * g;
    bf16x8 pb0[4], pb1[4];
#pragma unroll
    for (int s = 0; s < 4; ++s) {
        int off = (s >> 1) * 8192 + (s & 1) * 4096;
        pb0[s] = *(const bf16x8*)&b_base[off];
        pb1[s] = *(const bf16x8*)&b_base[off + 512];
    }

    // LDS-only barrier
    asm volatile("s_waitcnt lgkmcnt(0)" ::: "memory");
    __builtin_amdgcn_s_barrier();
    asm volatile("" ::: "memory");

    // ---- Phase 3: 16 K-steps, each B-pair feeds BOTH tiles (4 MFMA) ----
    f32x4 a00 = {0.f, 0.f, 0.f, 0.f}, a01 = {0.f, 0.f, 0.f, 0.f};
    f32x4 a10 = {0.f, 0.f, 0.f, 0.f}, a11 = {0.f, 0.f, 0.f, 0.f};
    __builtin_amdgcn_s_setprio(1);
#pragma unroll
    for (int s = 0; s < 16; ++s) {
        int abyte = ln * 1024 + 16 * ((4 * s + g) ^ (ln & 7));
        bf16x8 af0 = *(const bf16x8*)((const char*)ps + abyte);
        bf16x8 af1 = *(const bf16x8*)((const char*)ps + 16384 + abyte);
        a00 = __builtin_amdgcn_mfma_f32_16x16x32_bf16(af0, pb0[s & 3], a00, 0, 0, 0);
        a01 = __builtin_amdgcn_mfma_f32_16x16x32_bf16(af0, pb1[s & 3], a01, 0, 0, 0);
        a10 = __builtin_amdgcn_mfma_f32_16x16x32_bf16(af1, pb0[s & 3], a10, 0, 0, 0);
        a11 = __builtin_amdgcn_mfma_f32_16x16x32_bf16(af1, pb1[s & 3], a11, 0, 0, 0);
        if (s < 12) {
            int off = ((s + 4) >> 1) * 8192 + ((s + 4) & 1) * 4096;
            pb0[s & 3] = *(const bf16x8*)&b_base[off];
            pb1[s & 3] = *(const bf16x8*)&b_base[off + 512];
        }
    }
    __builtin_amdgcn_s_setprio(0);

    // ---- Phase 2 (moved): attn stores, flat fully-coalesced re-read of ps ----
    {
        float* ab = out_attn + ((size_t)(u * II + i0)) * JJ;
#pragma unroll
        for (int k = 0; k < 16; ++k) {
            int f = t + 256 * k;            // [0, 4096) x 4-float chunks
            int row = f >> 7;               // [0, 32)
            int j4 = (f & 127) * 4;         // [0, 512)
            int gcol = j4 >> 3, half = (j4 >> 2) & 1;
            int tl = row >> 4, rw = row & 15;
            uint2 qv = *(const uint2*)((const char*)ps + tl * 16384 + rw * 1024 +
                                       16 * (gcol ^ (rw & 7)) + 8 * half);
            float dv = dinv_lds[row];
            f32x4 v;
            v[0] = __uint_as_float(qv.x << 16) * dv;
            v[1] = __uint_as_float(qv.x & 0xFFFF0000u) * dv;
            v[2] = __uint_as_float(qv.y << 16) * dv;
            v[3] = __uint_as_float(qv.y & 0xFFFF0000u) * dv;
            __builtin_nontemporal_store(v, (f32x4*)&ab[(size_t)row * JJ + j4]);
        }
    }

    // ---- W-frag prefetch (L2-hot 32KB; shared by both tiles) ----
    const short* wbase = wt_g + (32 * w + ln) * 32 + 8 * g;
    bf16x8 wb0[4], wb1[4];
#pragma unroll
    for (int ks = 0; ks < 4; ++ks) {
        wb0[ks] = *(const bf16x8*)&wbase[ks * 4096];
        wb1[ks] = *(const bf16x8*)&wbase[ks * 4096 + 512];
    }

    // barrier: all ps reads (attn) done -> overlay pooled into ps
    asm volatile("s_waitcnt lgkmcnt(0)" ::: "memory");
    __builtin_amdgcn_s_barrier();
    asm volatile("" ::: "memory");

    // ---- Phase 4: scale by dinv, pack bf16 -> swizzled pooled (overlay) ----
    {
        char* pool = (char*)ps;   // 32 rows x 256B, swizzled granules
        int c0 = 32 * w + ln, c1 = c0 + 16;
#pragma unroll
        for (int ri = 0; ri < 4; ++ri) {
            int row0 = 4 * g + ri, row1 = 16 + row0;
            float dv0 = dinv_lds[row0], dv1 = dinv_lds[row1];
            *(short*)(pool + row0 * 256 + 16 * ((c0 >> 3) ^ (row0 & 7)) +
                      2 * (ln & 7)) = bf16s(a00[ri] * dv0);
            *(short*)(pool + row0 * 256 + 16 * ((c1 >> 3) ^ (row0 & 7)) +
                      2 * (ln & 7)) = bf16s(a01[ri] * dv0);
            *(short*)(pool + row1 * 256 + 16 * ((c0 >> 3) ^ (row1 & 7)) +
                      2 * (ln & 7)) = bf16s(a10[ri] * dv1);
            *(short*)(pool + row1 * 256 + 16 * ((c1 >> 3) ^ (row1 & 7)) +
                      2 * (ln & 7)) = bf16s(a11[ri] * dv1);
        }
    }
    asm volatile("s_waitcnt lgkmcnt(0)" ::: "memory");
    __builtin_amdgcn_s_barrier();
    asm volatile("" ::: "memory");

    // ---- Phase 5: out = relu(u_part + pooled @ W_mlp[E:]) via MFMA ----
    f32x4 o00 = {0.f, 0.f, 0.f, 0.f}, o01 = {0.f, 0.f, 0.f, 0.f};
    f32x4 o10 = {0.f, 0.f, 0.f, 0.f}, o11 = {0.f, 0.f, 0.f, 0.f};
#pragma unroll
    for (int ks = 0; ks < 4; ++ks) {
        int pbyte0 = ln * 256 + 16 * ((4 * ks + g) ^ (ln & 7));
        bf16x8 pa0 = *(const bf16x8*)((const char*)ps + pbyte0);
        bf16x8 pa1 = *(const bf16x8*)((const char*)ps + 4096 + pbyte0);
        o00 = __builtin_amdgcn_mfma_f32_16x16x32_bf16(pa0, wb0[ks], o00, 0, 0, 0);
        o01 = __builtin_amdgcn_mfma_f32_16x16x32_bf16(pa0, wb1[ks], o01, 0, 0, 0);
        o10 = __builtin_amdgcn_mfma_f32_16x16x32_bf16(pa1, wb0[ks], o10, 0, 0, 0);
        o11 = __builtin_amdgcn_mfma_f32_16x16x32_bf16(pa1, wb1[ks], o11, 0, 0, 0);
    }
    {
        int c0 = 32 * w + ln, c1 = c0 + 16;
        float up0v = up_g[u * CC + c0];
        float up1v = up_g[u * CC + c1];
        float* ctx = out_ctx + ((size_t)(u * II + i0)) * CC;
#pragma unroll
        for (int ri = 0; ri < 4; ++ri) {
            int row0 = 4 * g + ri, row1 = 16 + row0;
            __builtin_nontemporal_store(fmaxf(o00[ri] + up0v, 0.f),
                                        &ctx[(size_t)row0 * CC + c0]);
            __builtin_nontemporal_store(fmaxf(o01[ri] + up1v, 0.f),
                                        &ctx[(size_t)row0 * CC + c1]);
            __builtin_nontemporal_store(fmaxf(o10[ri] + up0v, 0.f),
                                        &ctx[(size_t)row1 * CC + c0]);
            __builtin_nontemporal_store(fmaxf(o11[ri] + up1v, 0.f),
                                        &ctx[(size_t)row1 * CC + c1]);
        }
    }
}

// ---------------------------------------------------------------------------
// Fallback (ws too small): round-2 validated self-contained kernel.
// ---------------------------------------------------------------------------
__global__ __launch_bounds__(256, 3) void fused_fallback(
    const float* __restrict__ tgt, const float* __restrict__ itc,
    const float* __restrict__ user, const int* __restrict__ mask,
    const float* __restrict__ wd, const float* __restrict__ bd,
    const float* __restrict__ Wm, const float* __restrict__ bm,
    float* __restrict__ out_ctx, float* __restrict__ out_attn) {
    __shared__ __align__(16) short Vt[CC][VTP];
    __shared__ __align__(16) float pool[IBF][CC + 4];
    __shared__ __align__(16) float skv[JJ];
    __shared__ __align__(16) float stv[IBF];
    __shared__ __align__(16) float upv[CC];
    __shared__ __align__(16) float dinv_lds[IBF];
    __shared__ unsigned char mk[JJ];

    int b = blockIdx.x;
    int x = b & 7, q = b >> 3;
    int u = x + 8 * (q >> 4);
    int ib = q & 15;
    int i0 = ib * IBF;
    int t = threadIdx.x;

    mk[t] = (unsigned char)(mask[u * JJ + t] != 0);
    mk[t + 256] = (unsigned char)(mask[u * JJ + t + 256] != 0);

    {
        int lane = t & 63, w4 = t >> 6;
        float2 w2 = *(const float2*)&wd[CC + lane * 2];
        for (int r = w4; r < JJ; r += 4) {
            float2 a = *(const float2*)&itc[((size_t)u * JJ + r) * CC + lane * 2];
            float s = wave_reduce_add(a.x * w2.x + a.y * w2.y);
            if (lane == 0) skv[r] = s;
        }
        float2 w1 = *(const float2*)&wd[lane * 2];
        float bdv = bd[0];
        for (int r = w4; r < IBF; r += 4) {
            float2 a = *(const float2*)&tgt[((size_t)u * II + i0 + r) * CC + lane * 2];
            float s = wave_reduce_add(a.x * w1.x + a.y * w1.y);
            if (lane == 0) stv[r] = s + bdv;
        }
        if (t < CC) {
            float acc = bm[t];
            for (int e = 0; e < EE; ++e) acc += user[u * EE + e] * Wm[e * CC + t];
            upv[t] = acc;
        }
    }
    __syncthreads();

    const int l = t & 63;
    const int w = t >> 6;
    const int ln = l & 15;
    const int g = l >> 4;

    bf16x8 a[16];
    float rowsum = 0.0f;
    {
        float s = stv[ln];
#pragma unroll
        for (int t16 = 0; t16 < 16; ++t16) {
            int j = 32 * t16 + 8 * g;
            float4 k0 = *(const float4*)&skv[j];
            float4 k1 = *(const float4*)&skv[j + 4];
            unsigned m0 = *(const unsigned*)&mk[j];
            unsigned m1 = *(const unsigned*)&mk[j + 4];
            float pf[8];
            pf[0] = (m0 & 0x000000FFu) ? __expf(fast_tanh(s + k0.x)) : 0.0f;
            pf[1] = (m0 & 0x0000FF00u) ? __expf(fast_tanh(s + k0.y)) : 0.0f;
            pf[2] = (m0 & 0x00FF0000u) ? __expf(fast_tanh(s + k0.z)) : 0.0f;
            pf[3] = (m0 & 0xFF000000u) ? __expf(fast_tanh(s + k0.w)) : 0.0f;
            pf[4] = (m1 & 0x000000FFu) ? __expf(fast_tanh(s + k1.x)) : 0.0f;
            pf[5] = (m1 & 0x0000FF00u) ? __expf(fast_tanh(s + k1.y)) : 0.0f;
            pf[6] = (m1 & 0x00FF0000u) ? __expf(fast_tanh(s + k1.z)) : 0.0f;
            pf[7] = (m1 & 0xFF000000u) ? __expf(fast_tanh(s + k1.w)) : 0.0f;
            rowsum += pf[0] + pf[1] + pf[2] + pf[3] + pf[4] + pf[5] + pf[6] + pf[7];
            FragU cu;
            cu.u[0] = pack_bf16x2(pf[0], pf[1]);
            cu.u[1] = pack_bf16x2(pf[2], pf[3]);
            cu.u[2] = pack_bf16x2(pf[4], pf[5]);
            cu.u[3] = pack_bf16x2(pf[6], pf[7]);
            a[t16] = cu.v;
        }
    }
    rowsum += __shfl_xor(rowsum, 16, 64);
    rowsum += __shfl_xor(rowsum, 32, 64);
    float dinv = 1.0f / rowsum;
    if (t < 16) dinv_lds[t] = dinv;

    {
        float* abase = out_attn + ((size_t)(u * II + i0 + ln)) * JJ + 8 * g;
#pragma unroll
        for (int t16 = 0; t16 < 16; ++t16) {
            FragU cu; cu.v = a[t16];
            float f0 = __uint_as_float(cu.u[0] << 16) * dinv;
            float f1 = __uint_as_float(cu.u[0] & 0xFFFF0000u) * dinv;
            float f2 = __uint_as_float(cu.u[1] << 16) * dinv;
            float f3 = __uint_as_float(cu.u[1] & 0xFFFF0000u) * dinv;
            float f4 = __uint_as_float(cu.u[2] << 16) * dinv;
            float f5 = __uint_as_float(cu.u[2] & 0xFFFF0000u) * dinv;
            float f6 = __uint_as_float(cu.u[3] << 16) * dinv;
            float f7 = __uint_as_float(cu.u[3] & 0xFFFF0000u) * dinv;
            *(float4*)&abase[32 * t16] = make_float4(f0, f1, f2, f3);
            *(float4*)&abase[32 * t16 + 4] = make_float4(f4, f5, f6, f7);
        }
    }

    f32x4 acc0 = {0.f, 0.f, 0.f, 0.f};
    f32x4 acc1 = {0.f, 0.f, 0.f, 0.f};
    const float* Vu = itc + (size_t)u * JJ * CC;
    const int cg = t & 31;
    const int jp = t >> 5;
    const int n0 = w * 32;

    for (int jt = 0; jt < 8; ++jt) {
        int j0 = jt * JT;
        __syncthreads();
#pragma unroll
        for (int it = 0; it < 4; ++it) {
            int jl = 2 * (jp + 8 * it);
            const float* r0 = &Vu[(size_t)(j0 + jl) * CC];
            const float* r1 = r0 + CC;
#pragma unroll
            for (int qv = 0; qv < 4; ++qv) {
                int c = cg + 32 * qv;
                *(unsigned*)&Vt[c][jl] = pack_bf16x2(r0[c], r1[c]);
            }
        }
        __syncthreads();
#pragma unroll
        for (int kk = 0; kk < 2; ++kk) {
            bf16x8 b0 = *(const bf16x8*)&Vt[n0 + ln][32 * kk + 8 * g];
            bf16x8 b1 = *(const bf16x8*)&Vt[n0 + 16 + ln][32 * kk + 8 * g];
            acc0 = __builtin_amdgcn_mfma_f32_16x16x32_bf16(a[2 * jt + kk], b0,
                                                           acc0, 0, 0, 0);
            acc1 = __builtin_amdgcn_mfma_f32_16x16x32_bf16(a[2 * jt + kk], b1,
                                                           acc1, 0, 0, 0);
        }
    }

    __syncthreads();
    {
        float4 dv = *(const float4*)&dinv_lds[4 * g];
        float dvr[4] = {dv.x, dv.y, dv.z, dv.w};
#pragma unroll
        for (int r = 0; r < 4; ++r) {
            pool[4 * g + r][n0 + ln] = acc0[r] * dvr[r];
            pool[4 * g + r][n0 + 16 + ln] = acc1[r] * dvr[r];
        }
    }
    __syncthreads();

    {
        int tx = t & 15, ty = t >> 4;
        float o[8];
#pragma unroll
        for (int k = 0; k < 8; ++k) o[k] = 0.f;
#pragma unroll 4
        for (int k = 0; k < CC; ++k) {
            float pk = pool[ty][k];
            float4 w0 = *(const float4*)&Wm[(size_t)(EE + k) * CC + tx * 8];
            float4 w1 = *(const float4*)&Wm[(size_t)(EE + k) * CC + tx * 8 + 4];
            o[0] += pk * w0.x; o[1] += pk * w0.y; o[2] += pk * w0.z; o[3] += pk * w0.w;
            o[4] += pk * w1.x; o[5] += pk * w1.y; o[6] += pk * w1.z; o[7] += pk * w1.w;
        }
        float4 up0 = *(const float4*)&upv[tx * 8];
        float4 up1 = *(const float4*)&upv[tx * 8 + 4];
        float4 r0, r1;
        r0.x = fmaxf(o[0] + up0.x, 0.f); r0.y = fmaxf(o[1] + up0.y, 0.f);
        r0.z = fmaxf(o[2] + up0.z, 0.f); r0.w = fmaxf(o[3] + up0.w, 0.f);
        r1.x = fmaxf(o[4] + up1.x, 0.f); r1.y = fmaxf(o[5] + up1.y, 0.f);
        r1.z = fmaxf(o[6] + up1.z, 0.f); r1.w = fmaxf(o[7] + up1.w, 0.f);
        float* ctx = out_ctx + ((size_t)(u * II + i0 + ty)) * CC + tx * 8;
        *(float4*)&ctx[0] = r0;
        *(float4*)&ctx[4] = r1;
    }
}

// ---------------------------------------------------------------------------
extern "C" void kernel_launch(void* const* d_in, const int* in_sizes, int n_in,
                              void* d_out, int out_size, void* d_ws,
                              size_t ws_size, hipStream_t stream) {
    const float* tgt  = (const float*)d_in[0];
    const float* itc  = (const float*)d_in[1];
    const float* user = (const float*)d_in[2];
    const int*   mask = (const int*)d_in[3];
    const float* wd   = (const float*)d_in[4];
    const float* bd   = (const float*)d_in[5];
    const float* Wm   = (const float*)d_in[6];
    const float* bm   = (const float*)d_in[7];
    float* out_ctx  = (float*)d_out;
    float* out_attn = out_ctx + (size_t)UU * II * CC;

    size_t scalars = (size_t)(UU * JJ + UU * CC) * sizeof(float);
    size_t vt_bytes = (size_t)UU * NJT * 8192 * sizeof(short);
    size_t wt_bytes = (size_t)16384 * sizeof(short);
    size_t need = scalars + vt_bytes + wt_bytes;
    if (ws_size >= need) {
        float* sk_g = (float*)d_ws;
        float* up_g = sk_g + UU * JJ;
        short* vt_g = (short*)((char*)d_ws + scalars);
        short* wt_g = vt_g + (size_t)UU * NJT * 8192;
        int gridA = VT_BLOCKS + UP_BLOCKS + 1;
        precompute_kernel<<<gridA, 256, 0, stream>>>(itc, user, wd, Wm, bm,
                                                     sk_g, up_g, vt_g, wt_g);
        fused_main<<<UU * NIB2, 256, 0, stream>>>(tgt, mask, wd, bd, sk_g, up_g,
                                                  vt_g, wt_g, out_ctx, out_attn);
    } else {
        fused_fallback<<<UU * (II / IBF), 256, 0, stream>>>(
            tgt, itc, user, mask, wd, bd, Wm, bm, out_ctx, out_attn);
    }
}